// Round 27
// baseline (27.161 us; speedup 1.0000x reference)
//
#include <hip/hip_runtime.h>

// NODE ensemble forward — FINAL (best measured: 25.66us; identical-source
// distribution over 5 runs: 25.66/27.52/27.15/26.00/25.69 => noise ~+/-1.9us).
// Above-noise wins this session: R3 B-in-registers (44->31us), R15 XSTR=520
// 16B-aligned A-reads, fast_sigmoid (R16-validated). Diagnostics (R5/R8/R11/
// R16) localized the remaining cost: 63% pure-wait at 2 waves/SIMD lockstep,
// protected by the {128-VGPR allocator ceiling, 48KB/wave B-frags, 116KB LDS}
// triangle — 7 structural escape attempts regressed. Not a hardware roofline
// (both pipes <25% busy); a latency plateau whose escape (wave-specialization
// / split-N) exceeds the remaining validated search budget.
//
// B=16384, D=512, T=64, DEPTH=6, NCOL=384.

#define DD     512
#define NCOL   384
#define PKELT  (NCOL * DD)     // elements per pk copy (196608)
#define XSTR   520             // xs row stride (bf16): 1040B rows, 16B aligned
#define PRSTR  388             // pr row stride (bf16)

typedef __bf16 bf16_t;
typedef __bf16 bf16x8 __attribute__((ext_vector_type(8)));
typedef __bf16 bf16x4 __attribute__((ext_vector_type(4)));
typedef float  f32x4  __attribute__((ext_vector_type(4)));

static __device__ __forceinline__ float b2f(unsigned int u16) {
  unsigned int t = u16 << 16;
  float f;
  __builtin_memcpy(&f, &t, 4);
  return f;
}

static __device__ __forceinline__ float fast_sigmoid(float z) {
  float e = __builtin_amdgcn_exp2f(z * -1.44269504f);
  return __builtin_amdgcn_rcpf(1.0f + e);
}

// pk[c][((cf*16 + ksg)*64 + lane)*8 + j] = fsel[cf*16+(lane&15)][ksg*32+(lane>>4)*8+j]
// replicated x8 (one copy per XCD's L2)
__global__ __launch_bounds__(256) void node_pack(const float* __restrict__ fsel,
                                                 bf16_t* __restrict__ pk)
{
  int tid  = blockIdx.x * 256 + threadIdx.x;   // 0..24575
  int lane = tid & 63;
  int ksg  = (tid >> 6) & 15;
  int cf   = tid >> 10;                        // 0..23
  int col  = cf * 16 + (lane & 15);
  int k    = ksg * 32 + (lane >> 4) * 8;
  float4 f0 = *reinterpret_cast<const float4*>(fsel + (size_t)col * DD + k);
  float4 f1 = *reinterpret_cast<const float4*>(fsel + (size_t)col * DD + k + 4);
  bf16x8 v;
  v[0] = (bf16_t)f0.x; v[1] = (bf16_t)f0.y; v[2] = (bf16_t)f0.z; v[3] = (bf16_t)f0.w;
  v[4] = (bf16_t)f1.x; v[5] = (bf16_t)f1.y; v[6] = (bf16_t)f1.z; v[7] = (bf16_t)f1.w;
  #pragma unroll
  for (int c = 0; c < 8; ++c)
    *reinterpret_cast<bf16x8*>(pk + (size_t)c * PKELT + (size_t)tid * 8) = v;
}

__global__ __launch_bounds__(512, 2) void node_fused(
    const float*  __restrict__ x,      // [B][512]
    const bf16_t* __restrict__ pk,     // packed B frags, x8 copies
    const float*  __restrict__ thr,    // [384]
    const float*  __restrict__ lw,     // [64][64]
    float*        __restrict__ out)    // [B]
{
  __shared__ bf16_t xs[64 * XSTR];     // 66560 B: full x block, bf16
  __shared__ bf16_t pr[64 * PRSTR];    // 49664 B: sigmoid probs

  const int tid  = threadIdx.x;
  const int lane = tid & 63;
  const int wv   = tid >> 6;           // 0..7; wave owns cols wv*48..+47
  const int rowblk = blockIdx.x * 64;
  const int c   = lane & 15;
  const int kg  = lane >> 4;

  const float* xr0 = x + (size_t)(rowblk + (tid >> 4)) * DD + ((tid & 15) << 2);
  const float* xr1 = xr0 + (size_t)32 * DD;
  bf16_t* xw0 = &xs[(tid >> 4) * XSTR + ((tid & 15) << 2)];
  bf16_t* xw1 = &xs[((tid >> 4) + 32) * XSTR + ((tid & 15) << 2)];

  float th[3];
  #pragma unroll
  for (int f = 0; f < 3; ++f) th[f] = thr[wv * 48 + f * 16 + c];

  float4 stg[2][2];

  #define ISSUE(n, buf)                                                         \
    do {                                                                        \
      int off_ = (n) * 64;                                                      \
      asm volatile("" : "+v"(off_));                                            \
      stg[buf][0] = *reinterpret_cast<const float4*>(xr0 + off_);               \
      stg[buf][1] = *reinterpret_cast<const float4*>(xr1 + off_);               \
    } while (0)

  #define WRITE(n, buf)                                                         \
    do {                                                                        \
      bf16x4 v0_, v1_;                                                          \
      v0_[0]=(bf16_t)stg[buf][0].x; v0_[1]=(bf16_t)stg[buf][0].y;               \
      v0_[2]=(bf16_t)stg[buf][0].z; v0_[3]=(bf16_t)stg[buf][0].w;               \
      v1_[0]=(bf16_t)stg[buf][1].x; v1_[1]=(bf16_t)stg[buf][1].y;               \
      v1_[2]=(bf16_t)stg[buf][1].z; v1_[3]=(bf16_t)stg[buf][1].w;               \
      *reinterpret_cast<bf16x4*>(xw0 + (n) * 64) = v0_;                         \
      *reinterpret_cast<bf16x4*>(xw1 + (n) * 64) = v1_;                         \
    } while (0)

  bf16x8 bh[3][2];
  #define LOAD_BH(n)                                                            \
    do {                                                                        \
      const bf16_t* q_ = pk + (size_t)(blockIdx.x & 7) * PKELT +                \
                         (size_t)lane * 8 + (size_t)(n) * 1024 +                \
                         (size_t)wv * 3 * 8192;                                 \
      asm volatile("" : "+v"(q_));                                              \
      _Pragma("unroll")                                                         \
      for (int f_ = 0; f_ < 3; ++f_)                                            \
        _Pragma("unroll")                                                       \
        for (int ks_ = 0; ks_ < 2; ++ks_)                                       \
          bh[f_][ks_] = *reinterpret_cast<const bf16x8*>(q_ + f_ * 8192 + ks_ * 512); \
    } while (0)

  // ---- prologue: chunks 0,1,2 issued; chunk 0 written; bh(0) after barrier ----
  ISSUE(0, 0);
  ISSUE(1, 1);
  WRITE(0, 0);                         // counted vmcnt waits stg[0] only
  ISSUE(2, 0);
  asm volatile("s_waitcnt lgkmcnt(0)" ::: "memory");
  __builtin_amdgcn_s_barrier();        // xs chunk 0 visible
  LOAD_BH(0);

  f32x4 acc[4][3];
  #pragma unroll
  for (int t = 0; t < 4; ++t)
    #pragma unroll
    for (int f = 0; f < 3; ++f) acc[t][f] = (f32x4){0.f, 0.f, 0.f, 0.f};

  // ---- 8-chunk pipelined GEMM (consume-before-refill discipline) ----
  #pragma unroll
  for (int ch = 0; ch < 8; ++ch) {
    #pragma unroll
    for (int t = 0; t < 4; ++t) {
      #pragma unroll
      for (int ks = 0; ks < 2; ++ks) {
        bf16x8 a = *reinterpret_cast<const bf16x8*>(
            &xs[(t * 16 + c) * XSTR + ch * 64 + ks * 32 + kg * 8]);
        acc[t][0] = __builtin_amdgcn_mfma_f32_16x16x32_bf16(a, bh[0][ks], acc[t][0], 0, 0, 0);
        acc[t][1] = __builtin_amdgcn_mfma_f32_16x16x32_bf16(a, bh[1][ks], acc[t][1], 0, 0, 0);
        acc[t][2] = __builtin_amdgcn_mfma_f32_16x16x32_bf16(a, bh[2][ks], acc[t][2], 0, 0, 0);
      }
    }
    if (ch < 7) {
      LOAD_BH(ch + 1);                 // WAR on bh regs: safe, MFMAs issued
      WRITE(ch + 1, (ch + 1) & 1);     // consume stg[buf] ...
      if (ch < 5) ISSUE(ch + 3, (ch + 1) & 1);   // ... THEN refill it
      asm volatile("s_waitcnt lgkmcnt(0)" ::: "memory");
      __builtin_amdgcn_s_barrier();    // xs chunk ch+1 visible
    }
  }
  #undef ISSUE
  #undef WRITE
  #undef LOAD_BH

  // ---- sigmoid -> pr. D: row = t*16 + kg*4 + r, col = wv*48 + f*16 + c ----
  #pragma unroll
  for (int t = 0; t < 4; ++t) {
    #pragma unroll
    for (int f = 0; f < 3; ++f) {
      const int col = wv * 48 + f * 16 + c;
      #pragma unroll
      for (int r = 0; r < 4; ++r) {
        const int row = t * 16 + kg * 4 + r;
        pr[row * PRSTR + col] = (bf16_t)fast_sigmoid(acc[t][f][r] - th[f]);
      }
    }
  }
  asm volatile("s_waitcnt lgkmcnt(0)" ::: "memory");
  __builtin_amdgcn_s_barrier();        // pr complete

  // ---- fold: lane = tree; two 32-leaf half-trees (peak live ~92 regs) ----
  float p0v[8], hv0[8], hv1[8];
  #pragma unroll
  for (int half = 0; half < 2; ++half) {
    float wch[32];
    #pragma unroll
    for (int j = 0; j < 8; ++j) {
      float4 f4 = *reinterpret_cast<const float4*>(lw + (size_t)lane * 64 + half * 32 + j * 4);
      wch[4*j] = f4.x; wch[4*j+1] = f4.y; wch[4*j+2] = f4.z; wch[4*j+3] = f4.w;
    }
    #pragma unroll
    for (int rr = 0; rr < 8; ++rr) {
      const int row = wv * 8 + rr;
      const unsigned int* prow =
          reinterpret_cast<const unsigned int*>(&pr[row * PRSTR]) + lane * 3;
      unsigned int d0 = prow[0], d1 = prow[1], d2 = prow[2];
      float p1 = b2f(d0 >> 16);
      float p2 = b2f(d1 & 0xffffu), p3 = b2f(d1 >> 16);
      float p4 = b2f(d2 & 0xffffu), p5 = b2f(d2 >> 16);
      if (half == 0) p0v[rr] = b2f(d0 & 0xffffu);

      float v[16];
      #pragma unroll
      for (int j = 0; j < 16; ++j) v[j] = fmaf(p5, wch[2*j] - wch[2*j+1], wch[2*j+1]);
      #pragma unroll
      for (int j = 0; j < 8;  ++j) v[j] = fmaf(p4, v[2*j] - v[2*j+1], v[2*j+1]);
      #pragma unroll
      for (int j = 0; j < 4;  ++j) v[j] = fmaf(p3, v[2*j] - v[2*j+1], v[2*j+1]);
      #pragma unroll
      for (int j = 0; j < 2;  ++j) v[j] = fmaf(p2, v[2*j] - v[2*j+1], v[2*j+1]);
      float s = fmaf(p1, v[0] - v[1], v[1]);
      if (half == 0) hv0[rr] = s; else hv1[rr] = s;
    }
  }

  float tvv[8];
  #pragma unroll
  for (int rr = 0; rr < 8; ++rr)
    tvv[rr] = fmaf(p0v[rr], hv0[rr] - hv1[rr], hv1[rr]);

  #pragma unroll
  for (int off = 32; off; off >>= 1) {
    #pragma unroll
    for (int rr = 0; rr < 8; ++rr) tvv[rr] += __shfl_xor(tvv[rr], off, 64);
  }
  if (lane == 0) {
    #pragma unroll
    for (int rr = 0; rr < 8; ++rr) out[rowblk + wv * 8 + rr] = tvv[rr];
  }
}

extern "C" void kernel_launch(void* const* d_in, const int* in_sizes, int n_in,
                              void* d_out, int out_size, void* d_ws, size_t ws_size,
                              hipStream_t stream) {
  const float* x    = (const float*)d_in[0];
  const float* fsel = (const float*)d_in[1];
  const float* thr  = (const float*)d_in[2];
  const float* lw   = (const float*)d_in[3];
  float* out = (float*)d_out;

  bf16_t* pk = (bf16_t*)d_ws;                 // 8 x 393216 B

  const int B = in_sizes[0] / DD;             // 16384

  node_pack<<<dim3(96), dim3(256), 0, stream>>>(fsel, pk);
  node_fused<<<dim3(B / 64), dim3(512), 0, stream>>>(x, pk, thr, lw, out);
}

// Round 28
// 25.330 us; speedup vs baseline: 1.0723x; 1.0723x over previous
//
#include <hip/hip_runtime.h>

// NODE ensemble forward — FINAL (best measured: 25.66us; identical-source
// distribution over 6 runs: 25.66/27.52/27.15/26.00/25.69/27.16,
// mean 26.5 +/- 0.8 => noise band ~+/-1.9us).
// Above-noise wins this session: R3 B-in-registers (44->31us), R15 XSTR=520
// 16B-aligned A-reads, fast_sigmoid (R16-validated). Diagnostics (R5/R8/R11/
// R16) localized the remaining cost: 63% pure-wait at 2 waves/SIMD lockstep,
// protected by the {128-VGPR allocator ceiling, 48KB/wave B-frags, 116KB LDS}
// triangle — 7 structural escape attempts regressed. Not a hardware roofline
// (both pipes <25% busy); a latency plateau whose escape (wave-specialization
// / split-N with pr-overlay + atomic partials) needs a fresh diagnostic
// budget beyond this session.
//
// B=16384, D=512, T=64, DEPTH=6, NCOL=384.

#define DD     512
#define NCOL   384
#define PKELT  (NCOL * DD)     // elements per pk copy (196608)
#define XSTR   520             // xs row stride (bf16): 1040B rows, 16B aligned
#define PRSTR  388             // pr row stride (bf16)

typedef __bf16 bf16_t;
typedef __bf16 bf16x8 __attribute__((ext_vector_type(8)));
typedef __bf16 bf16x4 __attribute__((ext_vector_type(4)));
typedef float  f32x4  __attribute__((ext_vector_type(4)));

static __device__ __forceinline__ float b2f(unsigned int u16) {
  unsigned int t = u16 << 16;
  float f;
  __builtin_memcpy(&f, &t, 4);
  return f;
}

static __device__ __forceinline__ float fast_sigmoid(float z) {
  float e = __builtin_amdgcn_exp2f(z * -1.44269504f);
  return __builtin_amdgcn_rcpf(1.0f + e);
}

// pk[c][((cf*16 + ksg)*64 + lane)*8 + j] = fsel[cf*16+(lane&15)][ksg*32+(lane>>4)*8+j]
// replicated x8 (one copy per XCD's L2)
__global__ __launch_bounds__(256) void node_pack(const float* __restrict__ fsel,
                                                 bf16_t* __restrict__ pk)
{
  int tid  = blockIdx.x * 256 + threadIdx.x;   // 0..24575
  int lane = tid & 63;
  int ksg  = (tid >> 6) & 15;
  int cf   = tid >> 10;                        // 0..23
  int col  = cf * 16 + (lane & 15);
  int k    = ksg * 32 + (lane >> 4) * 8;
  float4 f0 = *reinterpret_cast<const float4*>(fsel + (size_t)col * DD + k);
  float4 f1 = *reinterpret_cast<const float4*>(fsel + (size_t)col * DD + k + 4);
  bf16x8 v;
  v[0] = (bf16_t)f0.x; v[1] = (bf16_t)f0.y; v[2] = (bf16_t)f0.z; v[3] = (bf16_t)f0.w;
  v[4] = (bf16_t)f1.x; v[5] = (bf16_t)f1.y; v[6] = (bf16_t)f1.z; v[7] = (bf16_t)f1.w;
  #pragma unroll
  for (int c = 0; c < 8; ++c)
    *reinterpret_cast<bf16x8*>(pk + (size_t)c * PKELT + (size_t)tid * 8) = v;
}

__global__ __launch_bounds__(512, 2) void node_fused(
    const float*  __restrict__ x,      // [B][512]
    const bf16_t* __restrict__ pk,     // packed B frags, x8 copies
    const float*  __restrict__ thr,    // [384]
    const float*  __restrict__ lw,     // [64][64]
    float*        __restrict__ out)    // [B]
{
  __shared__ bf16_t xs[64 * XSTR];     // 66560 B: full x block, bf16
  __shared__ bf16_t pr[64 * PRSTR];    // 49664 B: sigmoid probs

  const int tid  = threadIdx.x;
  const int lane = tid & 63;
  const int wv   = tid >> 6;           // 0..7; wave owns cols wv*48..+47
  const int rowblk = blockIdx.x * 64;
  const int c   = lane & 15;
  const int kg  = lane >> 4;

  const float* xr0 = x + (size_t)(rowblk + (tid >> 4)) * DD + ((tid & 15) << 2);
  const float* xr1 = xr0 + (size_t)32 * DD;
  bf16_t* xw0 = &xs[(tid >> 4) * XSTR + ((tid & 15) << 2)];
  bf16_t* xw1 = &xs[((tid >> 4) + 32) * XSTR + ((tid & 15) << 2)];

  float th[3];
  #pragma unroll
  for (int f = 0; f < 3; ++f) th[f] = thr[wv * 48 + f * 16 + c];

  float4 stg[2][2];

  #define ISSUE(n, buf)                                                         \
    do {                                                                        \
      int off_ = (n) * 64;                                                      \
      asm volatile("" : "+v"(off_));                                            \
      stg[buf][0] = *reinterpret_cast<const float4*>(xr0 + off_);               \
      stg[buf][1] = *reinterpret_cast<const float4*>(xr1 + off_);               \
    } while (0)

  #define WRITE(n, buf)                                                         \
    do {                                                                        \
      bf16x4 v0_, v1_;                                                          \
      v0_[0]=(bf16_t)stg[buf][0].x; v0_[1]=(bf16_t)stg[buf][0].y;               \
      v0_[2]=(bf16_t)stg[buf][0].z; v0_[3]=(bf16_t)stg[buf][0].w;               \
      v1_[0]=(bf16_t)stg[buf][1].x; v1_[1]=(bf16_t)stg[buf][1].y;               \
      v1_[2]=(bf16_t)stg[buf][1].z; v1_[3]=(bf16_t)stg[buf][1].w;               \
      *reinterpret_cast<bf16x4*>(xw0 + (n) * 64) = v0_;                         \
      *reinterpret_cast<bf16x4*>(xw1 + (n) * 64) = v1_;                         \
    } while (0)

  bf16x8 bh[3][2];
  #define LOAD_BH(n)                                                            \
    do {                                                                        \
      const bf16_t* q_ = pk + (size_t)(blockIdx.x & 7) * PKELT +                \
                         (size_t)lane * 8 + (size_t)(n) * 1024 +                \
                         (size_t)wv * 3 * 8192;                                 \
      asm volatile("" : "+v"(q_));                                              \
      _Pragma("unroll")                                                         \
      for (int f_ = 0; f_ < 3; ++f_)                                            \
        _Pragma("unroll")                                                       \
        for (int ks_ = 0; ks_ < 2; ++ks_)                                       \
          bh[f_][ks_] = *reinterpret_cast<const bf16x8*>(q_ + f_ * 8192 + ks_ * 512); \
    } while (0)

  // ---- prologue: chunks 0,1,2 issued; chunk 0 written; bh(0) after barrier ----
  ISSUE(0, 0);
  ISSUE(1, 1);
  WRITE(0, 0);                         // counted vmcnt waits stg[0] only
  ISSUE(2, 0);
  asm volatile("s_waitcnt lgkmcnt(0)" ::: "memory");
  __builtin_amdgcn_s_barrier();        // xs chunk 0 visible
  LOAD_BH(0);

  f32x4 acc[4][3];
  #pragma unroll
  for (int t = 0; t < 4; ++t)
    #pragma unroll
    for (int f = 0; f < 3; ++f) acc[t][f] = (f32x4){0.f, 0.f, 0.f, 0.f};

  // ---- 8-chunk pipelined GEMM (consume-before-refill discipline) ----
  #pragma unroll
  for (int ch = 0; ch < 8; ++ch) {
    #pragma unroll
    for (int t = 0; t < 4; ++t) {
      #pragma unroll
      for (int ks = 0; ks < 2; ++ks) {
        bf16x8 a = *reinterpret_cast<const bf16x8*>(
            &xs[(t * 16 + c) * XSTR + ch * 64 + ks * 32 + kg * 8]);
        acc[t][0] = __builtin_amdgcn_mfma_f32_16x16x32_bf16(a, bh[0][ks], acc[t][0], 0, 0, 0);
        acc[t][1] = __builtin_amdgcn_mfma_f32_16x16x32_bf16(a, bh[1][ks], acc[t][1], 0, 0, 0);
        acc[t][2] = __builtin_amdgcn_mfma_f32_16x16x32_bf16(a, bh[2][ks], acc[t][2], 0, 0, 0);
      }
    }
    if (ch < 7) {
      LOAD_BH(ch + 1);                 // WAR on bh regs: safe, MFMAs issued
      WRITE(ch + 1, (ch + 1) & 1);     // consume stg[buf] ...
      if (ch < 5) ISSUE(ch + 3, (ch + 1) & 1);   // ... THEN refill it
      asm volatile("s_waitcnt lgkmcnt(0)" ::: "memory");
      __builtin_amdgcn_s_barrier();    // xs chunk ch+1 visible
    }
  }
  #undef ISSUE
  #undef WRITE
  #undef LOAD_BH

  // ---- sigmoid -> pr. D: row = t*16 + kg*4 + r, col = wv*48 + f*16 + c ----
  #pragma unroll
  for (int t = 0; t < 4; ++t) {
    #pragma unroll
    for (int f = 0; f < 3; ++f) {
      const int col = wv * 48 + f * 16 + c;
      #pragma unroll
      for (int r = 0; r < 4; ++r) {
        const int row = t * 16 + kg * 4 + r;
        pr[row * PRSTR + col] = (bf16_t)fast_sigmoid(acc[t][f][r] - th[f]);
      }
    }
  }
  asm volatile("s_waitcnt lgkmcnt(0)" ::: "memory");
  __builtin_amdgcn_s_barrier();        // pr complete

  // ---- fold: lane = tree; two 32-leaf half-trees (peak live ~92 regs) ----
  float p0v[8], hv0[8], hv1[8];
  #pragma unroll
  for (int half = 0; half < 2; ++half) {
    float wch[32];
    #pragma unroll
    for (int j = 0; j < 8; ++j) {
      float4 f4 = *reinterpret_cast<const float4*>(lw + (size_t)lane * 64 + half * 32 + j * 4);
      wch[4*j] = f4.x; wch[4*j+1] = f4.y; wch[4*j+2] = f4.z; wch[4*j+3] = f4.w;
    }
    #pragma unroll
    for (int rr = 0; rr < 8; ++rr) {
      const int row = wv * 8 + rr;
      const unsigned int* prow =
          reinterpret_cast<const unsigned int*>(&pr[row * PRSTR]) + lane * 3;
      unsigned int d0 = prow[0], d1 = prow[1], d2 = prow[2];
      float p1 = b2f(d0 >> 16);
      float p2 = b2f(d1 & 0xffffu), p3 = b2f(d1 >> 16);
      float p4 = b2f(d2 & 0xffffu), p5 = b2f(d2 >> 16);
      if (half == 0) p0v[rr] = b2f(d0 & 0xffffu);

      float v[16];
      #pragma unroll
      for (int j = 0; j < 16; ++j) v[j] = fmaf(p5, wch[2*j] - wch[2*j+1], wch[2*j+1]);
      #pragma unroll
      for (int j = 0; j < 8;  ++j) v[j] = fmaf(p4, v[2*j] - v[2*j+1], v[2*j+1]);
      #pragma unroll
      for (int j = 0; j < 4;  ++j) v[j] = fmaf(p3, v[2*j] - v[2*j+1], v[2*j+1]);
      #pragma unroll
      for (int j = 0; j < 2;  ++j) v[j] = fmaf(p2, v[2*j] - v[2*j+1], v[2*j+1]);
      float s = fmaf(p1, v[0] - v[1], v[1]);
      if (half == 0) hv0[rr] = s; else hv1[rr] = s;
    }
  }

  float tvv[8];
  #pragma unroll
  for (int rr = 0; rr < 8; ++rr)
    tvv[rr] = fmaf(p0v[rr], hv0[rr] - hv1[rr], hv1[rr]);

  #pragma unroll
  for (int off = 32; off; off >>= 1) {
    #pragma unroll
    for (int rr = 0; rr < 8; ++rr) tvv[rr] += __shfl_xor(tvv[rr], off, 64);
  }
  if (lane == 0) {
    #pragma unroll
    for (int rr = 0; rr < 8; ++rr) out[rowblk + wv * 8 + rr] = tvv[rr];
  }
}

extern "C" void kernel_launch(void* const* d_in, const int* in_sizes, int n_in,
                              void* d_out, int out_size, void* d_ws, size_t ws_size,
                              hipStream_t stream) {
  const float* x    = (const float*)d_in[0];
  const float* fsel = (const float*)d_in[1];
  const float* thr  = (const float*)d_in[2];
  const float* lw   = (const float*)d_in[3];
  float* out = (float*)d_out;

  bf16_t* pk = (bf16_t*)d_ws;                 // 8 x 393216 B

  const int B = in_sizes[0] / DD;             // 16384

  node_pack<<<dim3(96), dim3(256), 0, stream>>>(fsel, pk);
  node_fused<<<dim3(B / 64), dim3(512), 0, stream>>>(x, pk, thr, lw, out);
}